// Round 1
// baseline (717.459 us; speedup 1.0000x reference)
//
#include <hip/hip_runtime.h>
#include <math.h>

#define FIN 512
#define FH 128
#define FOUT 40

// ---------------- CSR build ----------------

__global__ void k_zero_int(int* __restrict__ p, int n){
  int i = blockIdx.x*256 + threadIdx.x;
  if(i<n) p[i]=0;
}

__global__ void k_count(const int* __restrict__ dst, int e, int* __restrict__ cnt){
  int i = blockIdx.x*256 + threadIdx.x;
  if(i<e) atomicAdd(&cnt[dst[i]],1);
}

// chunk = 1024 elems per block (256 thr x 4)
__global__ void k_scan_a(const int* __restrict__ cnt, int n, int* __restrict__ rp, int* __restrict__ aux){
  __shared__ int sh[256];
  int t = threadIdx.x;
  int base = blockIdx.x*1024;
  int v[4]; int s = 0;
  #pragma unroll
  for(int j=0;j<4;j++){ int idx = base + t*4 + j; int x = (idx<n)?cnt[idx]:0; v[j]=x; s+=x; }
  sh[t]=s; __syncthreads();
  for(int off=1; off<256; off<<=1){
    int x = (t>=off)? sh[t-off]:0; __syncthreads();
    sh[t]+=x; __syncthreads();
  }
  int run = (t>0)? sh[t-1]:0;
  #pragma unroll
  for(int j=0;j<4;j++){ run += v[j]; int idx = base + t*4 + j; if(idx<n) rp[idx+1]=run; }
  if(t==255) aux[blockIdx.x]=sh[255];
}

// single block: exclusive scan of aux[nchunks] in place (nchunks <= 256)
__global__ void k_scan_b(int* __restrict__ aux, int nchunks){
  __shared__ int sh[256];
  int t = threadIdx.x;
  sh[t] = (t<nchunks)? aux[t] : 0;
  __syncthreads();
  for(int off=1; off<256; off<<=1){
    int x = (t>=off)? sh[t-off]:0; __syncthreads();
    sh[t]+=x; __syncthreads();
  }
  if(t<nchunks) aux[t] = (t>0)? sh[t-1] : 0;
  __syncthreads();
}

__global__ void k_scan_c(int* __restrict__ rp, const int* __restrict__ aux, int n){
  int i = blockIdx.x*256 + threadIdx.x;
  if(i<n) rp[i+1] += aux[i>>10];
  if(i==0) rp[0] = 0;
}

__global__ void k_dinv(const int* __restrict__ cnt, float* __restrict__ dinv, int n){
  int i = blockIdx.x*256 + threadIdx.x;
  if(i<n) dinv[i] = rsqrtf((float)(cnt[i]+1));
}

__global__ void k_fill(const int* __restrict__ src, const int* __restrict__ dst, int e,
                       const int* __restrict__ rp, int* __restrict__ cursor, int* __restrict__ srcs){
  int i = blockIdx.x*256 + threadIdx.x;
  if(i<e){
    int d = dst[i];
    int p = rp[d] + atomicAdd(&cursor[d],1);
    srcs[p] = src[i];
  }
}

// ---------------- GEMM1: XW[n,128] = X[n,512] @ W1[512,128] (fp32) ----------------
// block: 256 thr, tile 64 rows x 128 cols, each thread 4 rows x 8 cols.
__global__ __launch_bounds__(256) void k_gemm1(const float* __restrict__ X, const float* __restrict__ W,
                                               float* __restrict__ XW, int n){
  __shared__ float Xs[32][64];    // [k][row] (transposed)
  __shared__ float Ws[32][128];   // [k][col]
  int t = threadIdx.x;
  int rowblk = blockIdx.x * 64;
  int rg = t >> 4;       // 0..15 -> rows rg*4 .. rg*4+3
  int cg = t & 15;       // 0..15 -> cols cg*8 .. cg*8+7
  float acc[4][8];
  #pragma unroll
  for(int r=0;r<4;r++)
    #pragma unroll
    for(int c=0;c<8;c++) acc[r][c]=0.f;

  for(int kt=0; kt<FIN; kt+=32){
    // load X tile (64 rows x 32 k), store transposed
    {
      int lrow = t >> 2;             // 0..63
      int lk   = (t & 3) * 8;        // 0,8,16,24
      int grow = rowblk + lrow; if(grow >= n) grow = n-1;
      const float* xp = X + (size_t)grow*FIN + kt + lk;
      float4 a0 = *(const float4*)xp;
      float4 a1 = *(const float4*)(xp+4);
      Xs[lk+0][lrow]=a0.x; Xs[lk+1][lrow]=a0.y; Xs[lk+2][lrow]=a0.z; Xs[lk+3][lrow]=a0.w;
      Xs[lk+4][lrow]=a1.x; Xs[lk+5][lrow]=a1.y; Xs[lk+6][lrow]=a1.z; Xs[lk+7][lrow]=a1.w;
    }
    // load W tile (32 k x 128 c)
    #pragma unroll
    for(int j=0;j<4;j++){
      int flat = j*1024 + t*4;
      int kk = flat >> 7, cc = flat & 127;
      *(float4*)&Ws[kk][cc] = *(const float4*)&W[(size_t)(kt+kk)*FH + cc];
    }
    __syncthreads();
    #pragma unroll
    for(int kk=0;kk<32;kk++){
      float4 xv = *(const float4*)&Xs[kk][rg*4];
      float4 w0 = *(const float4*)&Ws[kk][cg*8];
      float4 w1 = *(const float4*)&Ws[kk][cg*8+4];
      float xr[4] = {xv.x,xv.y,xv.z,xv.w};
      float wr[8] = {w0.x,w0.y,w0.z,w0.w,w1.x,w1.y,w1.z,w1.w};
      #pragma unroll
      for(int r=0;r<4;r++)
        #pragma unroll
        for(int c=0;c<8;c++) acc[r][c] += xr[r]*wr[c];
    }
    __syncthreads();
  }
  #pragma unroll
  for(int r=0;r<4;r++){
    int grow = rowblk + rg*4 + r;
    if(grow < n){
      float4 o0 = {acc[r][0],acc[r][1],acc[r][2],acc[r][3]};
      float4 o1 = {acc[r][4],acc[r][5],acc[r][6],acc[r][7]};
      *(float4*)&XW[(size_t)grow*FH + cg*8]   = o0;
      *(float4*)&XW[(size_t)grow*FH + cg*8+4] = o1;
    }
  }
}

// ---------------- agg1: H1 = relu(A_norm @ XW + b1), one wave per node ----------------
__global__ __launch_bounds__(256) void k_agg1(const float* __restrict__ XW, const int* __restrict__ rp,
                                              const int* __restrict__ srcs, const float* __restrict__ dinv,
                                              const float* __restrict__ b1, float* __restrict__ H1, int n){
  int d = blockIdx.x*4 + (threadIdx.x >> 6);
  if(d >= n) return;
  int lane = threadIdx.x & 63;
  int c = lane*2;
  float ax = 0.f, ay = 0.f;
  int beg = rp[d], end = rp[d+1];
  for(int j=beg;j<end;j++){
    int s = srcs[j];
    float ds = dinv[s];
    float2 v = *(const float2*)&XW[s*FH + c];
    ax += v.x*ds; ay += v.y*ds;
  }
  float dd = dinv[d];
  float2 sv = *(const float2*)&XW[d*FH + c];
  float2 bb = *(const float2*)&b1[c];
  float ox = ax*dd + sv.x*dd*dd + bb.x;
  float oy = ay*dd + sv.y*dd*dd + bb.y;
  ox = fmaxf(ox,0.f); oy = fmaxf(oy,0.f);
  float2 o = {ox,oy};
  *(float2*)&H1[d*FH + c] = o;
}

// ---------------- GEMM2: H2[n,40] = H1[n,128] @ W2[128,40] ----------------
__global__ __launch_bounds__(256) void k_gemm2(const float* __restrict__ H1, const float* __restrict__ W2,
                                               float* __restrict__ H2, int n){
  __shared__ float Hs[64][129];   // +1 pad: inner reads Hs[r][k] across lanes r -> conflict-free
  __shared__ float Ws[128][40];
  int t = threadIdx.x;
  for(int i=t;i<FH*FOUT;i+=256) Ws[i/FOUT][i%FOUT] = W2[i];
  int rowblk = blockIdx.x*64;
  #pragma unroll
  for(int j=0;j<8;j++){
    int flat = j*1024 + t*4;
    int row = flat >> 7, col = flat & 127;
    int grow = rowblk + row; if(grow >= n) grow = n-1;
    float4 v = *(const float4*)&H1[(size_t)grow*FH + col];
    Hs[row][col+0]=fmaxf(v.x,0.f); Hs[row][col+1]=fmaxf(v.y,0.f);
    Hs[row][col+2]=fmaxf(v.z,0.f); Hs[row][col+3]=fmaxf(v.w,0.f);
  }
  __syncthreads();
  int r = t & 63;
  int g = t >> 6;        // 0..3
  int c0 = g*10;
  float acc[10];
  #pragma unroll
  for(int j=0;j<10;j++) acc[j]=0.f;
  for(int k=0;k<FH;k++){
    float hv = Hs[r][k];
    #pragma unroll
    for(int j=0;j<10;j++) acc[j] += hv * Ws[k][c0+j];
  }
  int grow = rowblk + r;
  if(grow < n){
    #pragma unroll
    for(int j=0;j<10;j++) H2[(size_t)grow*FOUT + c0 + j] = acc[j];
  }
}

// ---------------- agg2 + bias + log_softmax, one wave per node ----------------
__global__ __launch_bounds__(256) void k_agg2_sm(const float* __restrict__ H2, const int* __restrict__ rp,
                                                 const int* __restrict__ srcs, const float* __restrict__ dinv,
                                                 const float* __restrict__ b2, float* __restrict__ out, int n){
  int d = blockIdx.x*4 + (threadIdx.x >> 6);
  if(d >= n) return;
  int lane = threadIdx.x & 63;
  bool act = lane < FOUT;
  float acc = 0.f;
  int beg = rp[d], end = rp[d+1];
  for(int j=beg;j<end;j++){
    int s = srcs[j];
    float ds = dinv[s];
    float v = act ? H2[s*FOUT + lane] : 0.f;
    acc += v*ds;
  }
  float dd = dinv[d];
  float sv = act ? H2[d*FOUT + lane] : 0.f;
  float bv = act ? b2[lane] : 0.f;
  float val = acc*dd + sv*dd*dd + bv;
  float m = act ? val : -3.402823466e38f;
  #pragma unroll
  for(int off=32; off; off>>=1) m = fmaxf(m, __shfl_xor(m, off));
  float ex = act ? expf(val - m) : 0.f;
  float ssum = ex;
  #pragma unroll
  for(int off=32; off; off>>=1) ssum += __shfl_xor(ssum, off);
  float ls = val - m - logf(ssum);
  if(act) out[d*FOUT + lane] = ls;
}

// ---------------- launch ----------------

extern "C" void kernel_launch(void* const* d_in, const int* in_sizes, int n_in,
                              void* d_out, int out_size, void* d_ws, size_t ws_size,
                              hipStream_t stream){
  const float* X  = (const float*)d_in[0];
  const int*   ei = (const int*)d_in[1];
  const float* W1 = (const float*)d_in[2];
  const float* b1 = (const float*)d_in[3];
  const float* W2 = (const float*)d_in[4];
  const float* b2 = (const float*)d_in[5];
  float* out = (float*)d_out;

  int n = in_sizes[0] / FIN;      // 100000
  int e = in_sizes[1] / 2;        // 1600000
  const int* src = ei;
  const int* dst = ei + e;

  // workspace layout (floats)
  float* XW   = (float*)d_ws;                 // n*128
  float* H1   = XW + (size_t)n*FH;            // n*128
  float* H2   = H1 + (size_t)n*FH;            // n*40
  float* dinv = H2 + (size_t)n*FOUT;          // n
  int* cnt    = (int*)(dinv + n);             // n
  int* cursor = cnt + n;                      // n
  int* rp     = cursor + n;                   // n+1
  int* srcs   = rp + (n+1) + 3;               // e
  int* aux    = srcs + e;                     // 256

  int nchunks = (n + 1023) / 1024;

  hipLaunchKernelGGL(k_zero_int, dim3((2*n+255)/256), dim3(256), 0, stream, cnt, 2*n);
  hipLaunchKernelGGL(k_count, dim3((e+255)/256), dim3(256), 0, stream, dst, e, cnt);
  hipLaunchKernelGGL(k_scan_a, dim3(nchunks), dim3(256), 0, stream, cnt, n, rp, aux);
  hipLaunchKernelGGL(k_scan_b, dim3(1), dim3(256), 0, stream, aux, nchunks);
  hipLaunchKernelGGL(k_scan_c, dim3((n+255)/256), dim3(256), 0, stream, rp, aux, n);
  hipLaunchKernelGGL(k_dinv, dim3((n+255)/256), dim3(256), 0, stream, cnt, dinv, n);
  hipLaunchKernelGGL(k_fill, dim3((e+255)/256), dim3(256), 0, stream, src, dst, e, rp, cursor, srcs);

  hipLaunchKernelGGL(k_gemm1, dim3((n+63)/64), dim3(256), 0, stream, X, W1, XW, n);
  hipLaunchKernelGGL(k_agg1, dim3((n+3)/4), dim3(256), 0, stream, XW, rp, srcs, dinv, b1, H1, n);
  hipLaunchKernelGGL(k_gemm2, dim3((n+63)/64), dim3(256), 0, stream, H1, W2, H2, n);
  hipLaunchKernelGGL(k_agg2_sm, dim3((n+3)/4), dim3(256), 0, stream, H2, rp, srcs, dinv, b2, out, n);
}

// Round 2
// 639.337 us; speedup vs baseline: 1.1222x; 1.1222x over previous
//
#include <hip/hip_runtime.h>
#include <math.h>

#define FIN 512
#define FH 128
#define FOUT 40

typedef __attribute__((ext_vector_type(8))) short bf16x8;
typedef __attribute__((ext_vector_type(4))) float f32x4;

__device__ inline ushort f2bf(float f){
  union { float f; uint32_t u; } v; v.f = f;
  uint32_t u = v.u;
  uint32_t r = (u + 0x7FFF + ((u >> 16) & 1)) >> 16;
  return (ushort)r;
}
__device__ inline float bflo(uint32_t v){ union { uint32_t u; float f; } x; x.u = v << 16; return x.f; }
__device__ inline float bfhi(uint32_t v){ union { uint32_t u; float f; } x; x.u = v & 0xFFFF0000u; return x.f; }

// ---------------- CSR build ----------------

__global__ void k_zero_int(int* __restrict__ p, int n){
  int i = blockIdx.x*256 + threadIdx.x;
  if(i<n) p[i]=0;
}

__global__ void k_count(const int* __restrict__ dst, int e, int* __restrict__ cnt){
  int i = blockIdx.x*256 + threadIdx.x;
  if(i<e) atomicAdd(&cnt[dst[i]],1);
}

__global__ void k_scan_a(const int* __restrict__ cnt, int n, int* __restrict__ rp, int* __restrict__ aux){
  __shared__ int sh[256];
  int t = threadIdx.x;
  int base = blockIdx.x*1024;
  int v[4]; int s = 0;
  #pragma unroll
  for(int j=0;j<4;j++){ int idx = base + t*4 + j; int x = (idx<n)?cnt[idx]:0; v[j]=x; s+=x; }
  sh[t]=s; __syncthreads();
  for(int off=1; off<256; off<<=1){
    int x = (t>=off)? sh[t-off]:0; __syncthreads();
    sh[t]+=x; __syncthreads();
  }
  int run = (t>0)? sh[t-1]:0;
  #pragma unroll
  for(int j=0;j<4;j++){ run += v[j]; int idx = base + t*4 + j; if(idx<n) rp[idx+1]=run; }
  if(t==255) aux[blockIdx.x]=sh[255];
}

__global__ void k_scan_b(int* __restrict__ aux, int nchunks){
  __shared__ int sh[256];
  int t = threadIdx.x;
  sh[t] = (t<nchunks)? aux[t] : 0;
  __syncthreads();
  for(int off=1; off<256; off<<=1){
    int x = (t>=off)? sh[t-off]:0; __syncthreads();
    sh[t]+=x; __syncthreads();
  }
  if(t<nchunks) aux[t] = (t>0)? sh[t-1] : 0;
}

__global__ void k_scan_c(int* __restrict__ rp, const int* __restrict__ aux, int n){
  int i = blockIdx.x*256 + threadIdx.x;
  if(i<n) rp[i+1] += aux[i>>10];
  if(i==0) rp[0] = 0;
}

__global__ void k_dinv(const int* __restrict__ cnt, float* __restrict__ dinv, int n){
  int i = blockIdx.x*256 + threadIdx.x;
  if(i<n) dinv[i] = rsqrtf((float)(cnt[i]+1));
}

__global__ void k_fill(const int* __restrict__ src, const int* __restrict__ dst, int e,
                       const int* __restrict__ rp, int* __restrict__ cursor, int* __restrict__ srcs){
  int i = blockIdx.x*256 + threadIdx.x;
  if(i<e){
    int d = dst[i];
    int p = rp[d] + atomicAdd(&cursor[d],1);
    srcs[p] = src[i];
  }
}

// ---------------- W1 prep: fp32 [512][128] -> bf16 transposed [128][512] ----------------
__global__ void k_prep(const float* __restrict__ W1, ushort* __restrict__ W1t){
  int i = blockIdx.x*256 + threadIdx.x;
  if(i < FIN*FH){
    int k = i / FH, c = i % FH;
    W1t[(size_t)c*FIN + k] = f2bf(W1[i]);
  }
}

// ---------------- GEMM1 via MFMA: XWbf[n,128] = bf16(X) @ bf16(W1) ----------------
// 256 thr = 4 waves; block tile 128 rows x 128 cols; wave = 32 rows x 128 cols.
// No LDS: A frags converted in-register from fp32 X; B frags from L2-resident W1t.
__global__ __launch_bounds__(256) void k_gemm1_mfma(const float* __restrict__ X,
                                                    const ushort* __restrict__ W1t,
                                                    ushort* __restrict__ XWbf, int n){
  int t = threadIdx.x;
  int lane = t & 63;
  int wid = t >> 6;
  int l15 = lane & 15;
  int lk8 = (lane >> 4) * 8;                 // 0,8,16,24
  int rowbase = blockIdx.x * 128 + wid * 32;

  int r0 = rowbase + l15;      if (r0 >= n) r0 = n-1;
  int r1 = rowbase + 16 + l15; if (r1 >= n) r1 = n-1;
  const float* a0p = X + (size_t)r0*FIN + lk8;
  const float* a1p = X + (size_t)r1*FIN + lk8;

  f32x4 acc[2][8];
  #pragma unroll
  for(int i=0;i<2;i++)
    #pragma unroll
    for(int j=0;j<8;j++) acc[i][j] = (f32x4){0.f,0.f,0.f,0.f};

  #pragma unroll 4
  for(int kc=0; kc<16; kc++){
    int k0 = kc*32;
    float4 a0a = *(const float4*)(a0p + k0);
    float4 a0b = *(const float4*)(a0p + k0 + 4);
    float4 a1a = *(const float4*)(a1p + k0);
    float4 a1b = *(const float4*)(a1p + k0 + 4);
    bf16x8 fa0, fa1;
    fa0[0]=(short)f2bf(a0a.x); fa0[1]=(short)f2bf(a0a.y); fa0[2]=(short)f2bf(a0a.z); fa0[3]=(short)f2bf(a0a.w);
    fa0[4]=(short)f2bf(a0b.x); fa0[5]=(short)f2bf(a0b.y); fa0[6]=(short)f2bf(a0b.z); fa0[7]=(short)f2bf(a0b.w);
    fa1[0]=(short)f2bf(a1a.x); fa1[1]=(short)f2bf(a1a.y); fa1[2]=(short)f2bf(a1a.z); fa1[3]=(short)f2bf(a1a.w);
    fa1[4]=(short)f2bf(a1b.x); fa1[5]=(short)f2bf(a1b.y); fa1[6]=(short)f2bf(a1b.z); fa1[7]=(short)f2bf(a1b.w);

    #pragma unroll
    for(int fj=0; fj<8; fj++){
      bf16x8 fb = *(const bf16x8*)(W1t + (size_t)(fj*16 + l15)*FIN + k0 + lk8);
      acc[0][fj] = __builtin_amdgcn_mfma_f32_16x16x32_bf16(fa0, fb, acc[0][fj], 0, 0, 0);
      acc[1][fj] = __builtin_amdgcn_mfma_f32_16x16x32_bf16(fa1, fb, acc[1][fj], 0, 0, 0);
    }
  }

  // epilogue: D layout col=lane&15, row=(lane>>4)*4+reg
  int rbase = (lane >> 4) * 4;
  #pragma unroll
  for(int fi=0; fi<2; fi++){
    #pragma unroll
    for(int r=0; r<4; r++){
      int row = rowbase + fi*16 + rbase + r;
      if(row < n){
        #pragma unroll
        for(int fj=0; fj<8; fj++){
          XWbf[(size_t)row*FH + fj*16 + l15] = f2bf(acc[fi][fj][r]);
        }
      }
    }
  }
}

// ---------------- agg1: H1 = relu(A_norm @ XW + b1), one wave per node, bf16 gather ----------------
__global__ __launch_bounds__(256) void k_agg1(const ushort* __restrict__ XWbf, const int* __restrict__ rp,
                                              const int* __restrict__ srcs, const float* __restrict__ dinv,
                                              const float* __restrict__ b1, float* __restrict__ H1, int n){
  int d = blockIdx.x*4 + (threadIdx.x >> 6);
  if(d >= n) return;
  int lane = threadIdx.x & 63;
  int c = lane*2;
  float ax = 0.f, ay = 0.f;
  int beg = rp[d], end = rp[d+1];
  for(int j=beg;j<end;j++){
    int s = srcs[j];
    float ds = dinv[s];
    uint32_t v = *(const uint32_t*)(XWbf + (size_t)s*FH + c);
    ax = fmaf(bflo(v), ds, ax);
    ay = fmaf(bfhi(v), ds, ay);
  }
  float dd = dinv[d];
  uint32_t sv = *(const uint32_t*)(XWbf + (size_t)d*FH + c);
  float2 bb = *(const float2*)&b1[c];
  float ox = ax*dd + bflo(sv)*dd*dd + bb.x;
  float oy = ay*dd + bfhi(sv)*dd*dd + bb.y;
  ox = fmaxf(ox,0.f); oy = fmaxf(oy,0.f);
  float2 o = {ox,oy};
  *(float2*)&H1[(size_t)d*FH + c] = o;
}

// ---------------- GEMM2: H2[n,40] = H1[n,128] @ W2[128,40] (fp32 VALU) ----------------
__global__ __launch_bounds__(256) void k_gemm2(const float* __restrict__ H1, const float* __restrict__ W2,
                                               float* __restrict__ H2, int n){
  __shared__ float Hs[64][129];
  __shared__ float Ws[128][40];
  int t = threadIdx.x;
  for(int i=t;i<FH*FOUT;i+=256) Ws[i/FOUT][i%FOUT] = W2[i];
  int rowblk = blockIdx.x*64;
  #pragma unroll
  for(int j=0;j<8;j++){
    int flat = j*1024 + t*4;
    int row = flat >> 7, col = flat & 127;
    int grow = rowblk + row; if(grow >= n) grow = n-1;
    float4 v = *(const float4*)&H1[(size_t)grow*FH + col];
    Hs[row][col+0]=v.x; Hs[row][col+1]=v.y;
    Hs[row][col+2]=v.z; Hs[row][col+3]=v.w;
  }
  __syncthreads();
  int r = t & 63;
  int g = t >> 6;
  int c0 = g*10;
  float acc[10];
  #pragma unroll
  for(int j=0;j<10;j++) acc[j]=0.f;
  for(int k=0;k<FH;k++){
    float hv = Hs[r][k];
    #pragma unroll
    for(int j=0;j<10;j++) acc[j] += hv * Ws[k][c0+j];
  }
  int grow = rowblk + r;
  if(grow < n){
    #pragma unroll
    for(int j=0;j<10;j++) H2[(size_t)grow*FOUT + c0 + j] = acc[j];
  }
}

// ---------------- agg2 + bias + log_softmax ----------------
__global__ __launch_bounds__(256) void k_agg2_sm(const float* __restrict__ H2, const int* __restrict__ rp,
                                                 const int* __restrict__ srcs, const float* __restrict__ dinv,
                                                 const float* __restrict__ b2, float* __restrict__ out, int n){
  int d = blockIdx.x*4 + (threadIdx.x >> 6);
  if(d >= n) return;
  int lane = threadIdx.x & 63;
  bool act = lane < FOUT;
  float acc = 0.f;
  int beg = rp[d], end = rp[d+1];
  for(int j=beg;j<end;j++){
    int s = srcs[j];
    float ds = dinv[s];
    float v = act ? H2[(size_t)s*FOUT + lane] : 0.f;
    acc += v*ds;
  }
  float dd = dinv[d];
  float sv = act ? H2[(size_t)d*FOUT + lane] : 0.f;
  float bv = act ? b2[lane] : 0.f;
  float val = acc*dd + sv*dd*dd + bv;
  float m = act ? val : -3.402823466e38f;
  #pragma unroll
  for(int off=32; off; off>>=1) m = fmaxf(m, __shfl_xor(m, off));
  float ex = act ? expf(val - m) : 0.f;
  float ssum = ex;
  #pragma unroll
  for(int off=32; off; off>>=1) ssum += __shfl_xor(ssum, off);
  float ls = val - m - logf(ssum);
  if(act) out[(size_t)d*FOUT + lane] = ls;
}

// ---------------- launch ----------------

extern "C" void kernel_launch(void* const* d_in, const int* in_sizes, int n_in,
                              void* d_out, int out_size, void* d_ws, size_t ws_size,
                              hipStream_t stream){
  const float* X  = (const float*)d_in[0];
  const int*   ei = (const int*)d_in[1];
  const float* W1 = (const float*)d_in[2];
  const float* b1 = (const float*)d_in[3];
  const float* W2 = (const float*)d_in[4];
  const float* b2 = (const float*)d_in[5];
  float* out = (float*)d_out;

  int n = in_sizes[0] / FIN;      // 100000
  int e = in_sizes[1] / 2;        // 1600000
  const int* src = ei;
  const int* dst = ei + e;

  // workspace layout
  ushort* XWbf = (ushort*)d_ws;                      // n*128 bf16
  ushort* W1t  = XWbf + (size_t)n*FH;                // 512*128 bf16
  float* H1    = (float*)(W1t + FIN*FH);             // n*128 f32
  float* H2    = H1 + (size_t)n*FH;                  // n*40
  float* dinv  = H2 + (size_t)n*FOUT;                // n
  int* cnt     = (int*)(dinv + n);                   // n
  int* cursor  = cnt + n;                            // n
  int* rp      = cursor + n;                         // n+1
  int* srcs    = rp + (n+1) + 3;                     // e
  int* aux     = srcs + e;                           // 256

  int nchunks = (n + 1023) / 1024;

  hipLaunchKernelGGL(k_zero_int, dim3((2*n+255)/256), dim3(256), 0, stream, cnt, 2*n);
  hipLaunchKernelGGL(k_count, dim3((e+255)/256), dim3(256), 0, stream, dst, e, cnt);
  hipLaunchKernelGGL(k_scan_a, dim3(nchunks), dim3(256), 0, stream, cnt, n, rp, aux);
  hipLaunchKernelGGL(k_scan_b, dim3(1), dim3(256), 0, stream, aux, nchunks);
  hipLaunchKernelGGL(k_scan_c, dim3((n+255)/256), dim3(256), 0, stream, rp, aux, n);
  hipLaunchKernelGGL(k_dinv, dim3((n+255)/256), dim3(256), 0, stream, cnt, dinv, n);
  hipLaunchKernelGGL(k_fill, dim3((e+255)/256), dim3(256), 0, stream, src, dst, e, rp, cursor, srcs);
  hipLaunchKernelGGL(k_prep, dim3((FIN*FH+255)/256), dim3(256), 0, stream, W1, W1t);

  hipLaunchKernelGGL(k_gemm1_mfma, dim3((n+127)/128), dim3(256), 0, stream, X, W1t, XWbf, n);
  hipLaunchKernelGGL(k_agg1, dim3((n+3)/4), dim3(256), 0, stream, XWbf, rp, srcs, dinv, b1, H1, n);
  hipLaunchKernelGGL(k_gemm2, dim3((n+63)/64), dim3(256), 0, stream, H1, W2, H2, n);
  hipLaunchKernelGGL(k_agg2_sm, dim3((n+3)/4), dim3(256), 0, stream, H2, rp, srcs, dinv, b2, out, n);
}

// Round 3
// 423.311 us; speedup vs baseline: 1.6949x; 1.5103x over previous
//
#include <hip/hip_runtime.h>
#include <math.h>

#define FIN 512
#define FH 128
#define FOUT 40
#define FP 64   // padded H2 width

typedef __attribute__((ext_vector_type(8))) short bf16x8;
typedef __attribute__((ext_vector_type(4))) float f32x4;

__device__ inline ushort f2bf(float f){
  union { float f; uint32_t u; } v; v.f = f;
  uint32_t u = v.u;
  uint32_t r = (u + 0x7FFF + ((u >> 16) & 1)) >> 16;
  return (ushort)r;
}
__device__ inline float bflo(uint32_t v){ union { uint32_t u; float f; } x; x.u = v << 16; return x.f; }
__device__ inline float bfhi(uint32_t v){ union { uint32_t u; float f; } x; x.u = v & 0xFFFF0000u; return x.f; }
__device__ inline uint32_t pk(float a, float b){ return (uint32_t)f2bf(a) | ((uint32_t)f2bf(b) << 16); }

// ---------------- CSR build ----------------

__global__ void k_zero_int(int* __restrict__ p, int n){
  int i = blockIdx.x*256 + threadIdx.x;
  if(i<n) p[i]=0;
}

__global__ void k_count(const int* __restrict__ dst, int e, int* __restrict__ cnt){
  int i = blockIdx.x*256 + threadIdx.x;
  if(i<e) atomicAdd(&cnt[dst[i]],1);
}

__global__ void k_scan_a(const int* __restrict__ cnt, int n, int* __restrict__ rp, int* __restrict__ aux){
  __shared__ int sh[256];
  int t = threadIdx.x;
  int base = blockIdx.x*1024;
  int v[4]; int s = 0;
  #pragma unroll
  for(int j=0;j<4;j++){ int idx = base + t*4 + j; int x = (idx<n)?cnt[idx]:0; v[j]=x; s+=x; }
  sh[t]=s; __syncthreads();
  for(int off=1; off<256; off<<=1){
    int x = (t>=off)? sh[t-off]:0; __syncthreads();
    sh[t]+=x; __syncthreads();
  }
  int run = (t>0)? sh[t-1]:0;
  #pragma unroll
  for(int j=0;j<4;j++){ run += v[j]; int idx = base + t*4 + j; if(idx<n) rp[idx+1]=run; }
  if(t==255) aux[blockIdx.x]=sh[255];
}

__global__ void k_scan_b(int* __restrict__ aux, int nchunks){
  __shared__ int sh[256];
  int t = threadIdx.x;
  sh[t] = (t<nchunks)? aux[t] : 0;
  __syncthreads();
  for(int off=1; off<256; off<<=1){
    int x = (t>=off)? sh[t-off]:0; __syncthreads();
    sh[t]+=x; __syncthreads();
  }
  if(t<nchunks) aux[t] = (t>0)? sh[t-1] : 0;
}

__global__ void k_scan_c(int* __restrict__ rp, const int* __restrict__ aux,
                         const int* __restrict__ cnt, float* __restrict__ dinv, int n){
  int i = blockIdx.x*256 + threadIdx.x;
  if(i<n){
    rp[i+1] += aux[i>>10];
    dinv[i] = rsqrtf((float)(cnt[i]+1));
  }
  if(i==0) rp[0] = 0;
}

__global__ void k_fill(const int* __restrict__ src, const int* __restrict__ dst, int e,
                       const int* __restrict__ rp, int* __restrict__ cursor, int* __restrict__ srcs){
  int i = blockIdx.x*256 + threadIdx.x;
  if(i<e){
    int d = dst[i];
    int p = rp[d] + atomicAdd(&cursor[d],1);
    srcs[p] = src[i];
  }
}

// ---------------- weight prep: W1 -> bf16 W1t[128][512]; W2 -> bf16 W2t[48][128] (pad 0) ---
__global__ void k_prep(const float* __restrict__ W1, const float* __restrict__ W2,
                       ushort* __restrict__ W1t, ushort* __restrict__ W2t){
  int i = blockIdx.x*256 + threadIdx.x;
  if(i < FIN*FH){
    int k = i / FH, c = i % FH;
    W1t[(size_t)c*FIN + k] = f2bf(W1[i]);
  }
  if(i < 48*FH){
    int c = i / FH, k = i % FH;
    W2t[i] = (c < FOUT) ? f2bf(W2[(size_t)k*FOUT + c]) : (ushort)0;
  }
}

// ---------------- GEMM1 via MFMA: XWs[n,128] = (bf16(X) @ bf16(W1)) * dinv[row] ----------------
__global__ __launch_bounds__(256) void k_gemm1_mfma(const float* __restrict__ X,
                                                    const ushort* __restrict__ W1t,
                                                    const float* __restrict__ dinv,
                                                    ushort* __restrict__ XWs, int n){
  int t = threadIdx.x;
  int lane = t & 63;
  int wid = t >> 6;
  int l15 = lane & 15;
  int lk8 = (lane >> 4) * 8;
  int rowbase = blockIdx.x * 128 + wid * 32;

  int r0 = rowbase + l15;      if (r0 >= n) r0 = n-1;
  int r1 = rowbase + 16 + l15; if (r1 >= n) r1 = n-1;
  const float* a0p = X + (size_t)r0*FIN + lk8;
  const float* a1p = X + (size_t)r1*FIN + lk8;

  f32x4 acc[2][8];
  #pragma unroll
  for(int i=0;i<2;i++)
    #pragma unroll
    for(int j=0;j<8;j++) acc[i][j] = (f32x4){0.f,0.f,0.f,0.f};

  #pragma unroll 4
  for(int kc=0; kc<16; kc++){
    int k0 = kc*32;
    float4 a0a = *(const float4*)(a0p + k0);
    float4 a0b = *(const float4*)(a0p + k0 + 4);
    float4 a1a = *(const float4*)(a1p + k0);
    float4 a1b = *(const float4*)(a1p + k0 + 4);
    bf16x8 fa0, fa1;
    fa0[0]=(short)f2bf(a0a.x); fa0[1]=(short)f2bf(a0a.y); fa0[2]=(short)f2bf(a0a.z); fa0[3]=(short)f2bf(a0a.w);
    fa0[4]=(short)f2bf(a0b.x); fa0[5]=(short)f2bf(a0b.y); fa0[6]=(short)f2bf(a0b.z); fa0[7]=(short)f2bf(a0b.w);
    fa1[0]=(short)f2bf(a1a.x); fa1[1]=(short)f2bf(a1a.y); fa1[2]=(short)f2bf(a1a.z); fa1[3]=(short)f2bf(a1a.w);
    fa1[4]=(short)f2bf(a1b.x); fa1[5]=(short)f2bf(a1b.y); fa1[6]=(short)f2bf(a1b.z); fa1[7]=(short)f2bf(a1b.w);

    #pragma unroll
    for(int fj=0; fj<8; fj++){
      bf16x8 fb = *(const bf16x8*)(W1t + (size_t)(fj*16 + l15)*FIN + k0 + lk8);
      acc[0][fj] = __builtin_amdgcn_mfma_f32_16x16x32_bf16(fa0, fb, acc[0][fj], 0, 0, 0);
      acc[1][fj] = __builtin_amdgcn_mfma_f32_16x16x32_bf16(fa1, fb, acc[1][fj], 0, 0, 0);
    }
  }

  int rbase = (lane >> 4) * 4;
  #pragma unroll
  for(int fi=0; fi<2; fi++){
    #pragma unroll
    for(int r=0; r<4; r++){
      int row = rowbase + fi*16 + rbase + r;
      if(row < n){
        float dd = dinv[row];
        #pragma unroll
        for(int fj=0; fj<8; fj++){
          XWs[(size_t)row*FH + fj*16 + l15] = f2bf(acc[fi][fj][r] * dd);
        }
      }
    }
  }
}

// ---------------- agg1: H1b = relu(dd*(sum_s XWs[s] + XWs[d]) + b1), bf16 out ----------------
// wave per node; 4 groups x 16 lanes; each group gathers a different edge row (uint4/lane).
__global__ __launch_bounds__(256) void k_agg1(const ushort* __restrict__ XWs, const int* __restrict__ rp,
                                              const int* __restrict__ srcs, const float* __restrict__ dinv,
                                              const float* __restrict__ b1, ushort* __restrict__ H1b, int n){
  int d = blockIdx.x*4 + (threadIdx.x >> 6);
  if(d >= n) return;
  int lane = threadIdx.x & 63;
  int g = lane >> 4, li = lane & 15;
  float acc[8] = {0.f,0.f,0.f,0.f,0.f,0.f,0.f,0.f};
  int beg = rp[d], end = rp[d+1];
  for(int j = beg + g; j < end; j += 4){
    int s = srcs[j];
    uint4 v = *(const uint4*)(XWs + (size_t)s*FH + li*8);
    acc[0]+=bflo(v.x); acc[1]+=bfhi(v.x); acc[2]+=bflo(v.y); acc[3]+=bfhi(v.y);
    acc[4]+=bflo(v.z); acc[5]+=bfhi(v.z); acc[6]+=bflo(v.w); acc[7]+=bfhi(v.w);
  }
  #pragma unroll
  for(int k=0;k<8;k++){
    acc[k] += __shfl_xor(acc[k], 16);
    acc[k] += __shfl_xor(acc[k], 32);
  }
  // self + epilogue
  uint4 sv = *(const uint4*)(XWs + (size_t)d*FH + li*8);
  float dd = dinv[d];
  float4 bb0 = *(const float4*)&b1[li*8];
  float4 bb1 = *(const float4*)&b1[li*8+4];
  float o0 = fmaxf((acc[0]+bflo(sv.x))*dd + bb0.x, 0.f);
  float o1 = fmaxf((acc[1]+bfhi(sv.x))*dd + bb0.y, 0.f);
  float o2 = fmaxf((acc[2]+bflo(sv.y))*dd + bb0.z, 0.f);
  float o3 = fmaxf((acc[3]+bfhi(sv.y))*dd + bb0.w, 0.f);
  float o4 = fmaxf((acc[4]+bflo(sv.z))*dd + bb1.x, 0.f);
  float o5 = fmaxf((acc[5]+bfhi(sv.z))*dd + bb1.y, 0.f);
  float o6 = fmaxf((acc[6]+bflo(sv.w))*dd + bb1.z, 0.f);
  float o7 = fmaxf((acc[7]+bfhi(sv.w))*dd + bb1.w, 0.f);
  if(g == 0){
    uint4 w;
    w.x = pk(o0,o1); w.y = pk(o2,o3); w.z = pk(o4,o5); w.w = pk(o6,o7);
    *(uint4*)(H1b + (size_t)d*FH + li*8) = w;
  }
}

// ---------------- GEMM2 via MFMA: H2s[n,64] = (H1b @ W2) * dinv[row], bf16, cols>=40 zero ---
__global__ __launch_bounds__(256) void k_gemm2_mfma(const ushort* __restrict__ H1b,
                                                    const ushort* __restrict__ W2t,
                                                    const float* __restrict__ dinv,
                                                    ushort* __restrict__ H2s, int n){
  int t = threadIdx.x;
  int lane = t & 63;
  int wid = t >> 6;
  int l15 = lane & 15;
  int lk8 = (lane >> 4) * 8;
  int rowbase = blockIdx.x * 128 + wid * 32;

  int r0 = rowbase + l15;      if (r0 >= n) r0 = n-1;
  int r1 = rowbase + 16 + l15; if (r1 >= n) r1 = n-1;
  const ushort* a0p = H1b + (size_t)r0*FH + lk8;
  const ushort* a1p = H1b + (size_t)r1*FH + lk8;

  f32x4 acc[2][3];
  #pragma unroll
  for(int i=0;i<2;i++)
    #pragma unroll
    for(int j=0;j<3;j++) acc[i][j] = (f32x4){0.f,0.f,0.f,0.f};

  #pragma unroll
  for(int kc=0; kc<4; kc++){
    int k0 = kc*32;
    bf16x8 fa0 = *(const bf16x8*)(a0p + k0);
    bf16x8 fa1 = *(const bf16x8*)(a1p + k0);
    #pragma unroll
    for(int fj=0; fj<3; fj++){
      bf16x8 fb = *(const bf16x8*)(W2t + (size_t)(fj*16 + l15)*FH + k0 + lk8);
      acc[0][fj] = __builtin_amdgcn_mfma_f32_16x16x32_bf16(fa0, fb, acc[0][fj], 0, 0, 0);
      acc[1][fj] = __builtin_amdgcn_mfma_f32_16x16x32_bf16(fa1, fb, acc[1][fj], 0, 0, 0);
    }
  }

  int rbase = (lane >> 4) * 4;
  #pragma unroll
  for(int fi=0; fi<2; fi++){
    #pragma unroll
    for(int r=0; r<4; r++){
      int row = rowbase + fi*16 + rbase + r;
      if(row < n){
        float dd = dinv[row];
        #pragma unroll
        for(int fj=0; fj<3; fj++){
          int col = fj*16 + l15;
          H2s[(size_t)row*FP + col] = (col < FOUT) ? f2bf(acc[fi][fj][r] * dd) : (ushort)0;
        }
        H2s[(size_t)row*FP + 48 + l15] = 0;
      }
    }
  }
}

// ---------------- agg2 + bias + log_softmax: out[d] = lsm(dd*(sum H2s[s] + H2s[d]) + b2) ---
__global__ __launch_bounds__(256) void k_agg2_sm(const ushort* __restrict__ H2s, const int* __restrict__ rp,
                                                 const int* __restrict__ srcs, const float* __restrict__ dinv,
                                                 const float* __restrict__ b2, float* __restrict__ out, int n){
  int d = blockIdx.x*4 + (threadIdx.x >> 6);
  if(d >= n) return;
  int lane = threadIdx.x & 63;
  int g = lane >> 4, li = lane & 15;
  float acc[4] = {0.f,0.f,0.f,0.f};
  int beg = rp[d], end = rp[d+1];
  for(int j = beg + g; j < end; j += 4){
    int s = srcs[j];
    uint2 v = *(const uint2*)(H2s + (size_t)s*FP + li*4);
    acc[0]+=bflo(v.x); acc[1]+=bfhi(v.x); acc[2]+=bflo(v.y); acc[3]+=bfhi(v.y);
  }
  #pragma unroll
  for(int k=0;k<4;k++){
    acc[k] += __shfl_xor(acc[k], 16);
    acc[k] += __shfl_xor(acc[k], 32);
  }
  uint2 sv = *(const uint2*)(H2s + (size_t)d*FP + li*4);
  acc[0]+=bflo(sv.x); acc[1]+=bfhi(sv.x); acc[2]+=bflo(sv.y); acc[3]+=bfhi(sv.y);
  float dd = dinv[d];
  float val[4];
  #pragma unroll
  for(int k=0;k<4;k++){
    int col = li*4 + k;
    float bv = (col < FOUT) ? b2[col] : 0.f;
    val[k] = (col < FOUT) ? (acc[k]*dd + bv) : -3.402823466e38f;
  }
  float m = fmaxf(fmaxf(val[0],val[1]), fmaxf(val[2],val[3]));
  #pragma unroll
  for(int off=1; off<16; off<<=1) m = fmaxf(m, __shfl_xor(m, off));
  float ssum = 0.f;
  #pragma unroll
  for(int k=0;k<4;k++){
    int col = li*4 + k;
    ssum += (col < FOUT) ? expf(val[k] - m) : 0.f;
  }
  #pragma unroll
  for(int off=1; off<16; off<<=1) ssum += __shfl_xor(ssum, off);
  float lse = m + logf(ssum);
  if(g == 0 && li < 10){
    float4 o = {val[0]-lse, val[1]-lse, val[2]-lse, val[3]-lse};
    *(float4*)&out[(size_t)d*FOUT + li*4] = o;
  }
}

// ---------------- launch ----------------

extern "C" void kernel_launch(void* const* d_in, const int* in_sizes, int n_in,
                              void* d_out, int out_size, void* d_ws, size_t ws_size,
                              hipStream_t stream){
  const float* X  = (const float*)d_in[0];
  const int*   ei = (const int*)d_in[1];
  const float* W1 = (const float*)d_in[2];
  const float* b1 = (const float*)d_in[3];
  const float* W2 = (const float*)d_in[4];
  const float* b2 = (const float*)d_in[5];
  float* out = (float*)d_out;

  int n = in_sizes[0] / FIN;      // 100000
  int e = in_sizes[1] / 2;        // 1600000
  const int* src = ei;
  const int* dst = ei + e;

  // workspace layout
  ushort* XWs = (ushort*)d_ws;                       // n*128 bf16 (dinv-scaled XW)
  ushort* H1b = XWs + (size_t)n*FH;                  // n*128 bf16
  ushort* H2s = H1b + (size_t)n*FH;                  // n*64  bf16 (dinv-scaled, padded)
  ushort* W1t = H2s + (size_t)n*FP;                  // 128*512
  ushort* W2t = W1t + (size_t)FH*FIN;                // 48*128
  float* dinv = (float*)(W2t + 48*FH);               // n
  int* cnt    = (int*)(dinv + n);                    // n
  int* cursor = cnt + n;                             // n
  int* rp     = cursor + n;                          // n+1
  int* srcs   = rp + (n+1) + 3;                      // e
  int* aux    = srcs + e;                            // 256

  int nchunks = (n + 1023) / 1024;

  hipLaunchKernelGGL(k_zero_int, dim3((2*n+255)/256), dim3(256), 0, stream, cnt, 2*n);
  hipLaunchKernelGGL(k_count, dim3((e+255)/256), dim3(256), 0, stream, dst, e, cnt);
  hipLaunchKernelGGL(k_scan_a, dim3(nchunks), dim3(256), 0, stream, cnt, n, rp, aux);
  hipLaunchKernelGGL(k_scan_b, dim3(1), dim3(256), 0, stream, aux, nchunks);
  hipLaunchKernelGGL(k_scan_c, dim3((n+255)/256), dim3(256), 0, stream, rp, aux, cnt, dinv, n);
  hipLaunchKernelGGL(k_fill, dim3((e+255)/256), dim3(256), 0, stream, src, dst, e, rp, cursor, srcs);
  hipLaunchKernelGGL(k_prep, dim3((FIN*FH+255)/256), dim3(256), 0, stream, W1, W2, W1t, W2t);

  hipLaunchKernelGGL(k_gemm1_mfma, dim3((n+127)/128), dim3(256), 0, stream, X, W1t, dinv, XWs, n);
  hipLaunchKernelGGL(k_agg1, dim3((n+3)/4), dim3(256), 0, stream, XWs, rp, srcs, dinv, b1, H1b, n);
  hipLaunchKernelGGL(k_gemm2_mfma, dim3((n+127)/128), dim3(256), 0, stream, H1b, W2t, dinv, H2s, n);
  hipLaunchKernelGGL(k_agg2_sm, dim3((n+3)/4), dim3(256), 0, stream, H2s, rp, srcs, dinv, b2, out, n);
}